// Round 10
// baseline (180.533 us; speedup 1.0000x reference)
//
#include <hip/hip_runtime.h>
#include <hip/hip_bf16.h>
#include <cstddef>

#define NB  4
#define NC  256
#define NN  4096
#define DQK 32
#define MT  64       // query rows per flash block
#define JT  64       // key tile per iteration
#define NIT (NN / JT)
#define XS2 264      // proj LDS row stride in bf16 ([32 n][256 c] + 8 pad)

typedef __attribute__((ext_vector_type(8))) short short8;
typedef __attribute__((ext_vector_type(4))) short short4v;
typedef __attribute__((ext_vector_type(4))) float f32x4;

#define MFMA16(a, b, c) __builtin_amdgcn_mfma_f32_16x16x32_bf16((a), (b), (c), 0, 0, 0)

__device__ inline unsigned pk2bf(float a, float b) {
  __hip_bfloat162 h = __float22bfloat162_rn(make_float2(a, b));
  unsigned u;
  __builtin_memcpy(&u, &h, 4);
  return u;
}

// async global->LDS, 16B per lane; LDS dest = uniform base + lane*16 (linear),
// global src is per-lane (pre-swizzled to realize the XOR'd LDS layout).
__device__ inline void gl16(const void* g, void* s) {
  __builtin_amdgcn_global_load_lds(
      (const __attribute__((address_space(1))) void*)g,
      (__attribute__((address_space(3))) void*)s, 16, 0, 0);
}

// ---- W convert: [Wq(32);Wk(32);Wv(256)] f32 -> W16[320][256] bf16 ----
__global__ __launch_bounds__(256) void wcvt_kernel(
    const float* __restrict__ Wq, const float* __restrict__ Wk,
    const float* __restrict__ Wv, __hip_bfloat16* __restrict__ W16) {
  const int id4 = (blockIdx.x * 256 + threadIdx.x) * 4;   // 80 blocks -> 81920
  const int row = id4 >> 8, col = id4 & 255;
  const float* src = (row < 32) ? Wq + row * 256
                   : (row < 64) ? Wk + (row - 32) * 256
                                : Wv + (row - 64) * 256;
  float4 vv = *(const float4*)(src + col);
  *(uint2*)(W16 + id4) = make_uint2(pk2bf(vv.x, vv.y), pk2bf(vv.z, vv.w));
}

// ---- fused proj (unchanged from round 9) ----
__global__ __launch_bounds__(256, 4) void proj_kernel(
    const float* __restrict__ x, const __hip_bfloat16* __restrict__ W16,
    const float* __restrict__ bq, const float* __restrict__ bk,
    const float* __restrict__ bv, __hip_bfloat16* __restrict__ q,
    __hip_bfloat16* __restrict__ kT, __hip_bfloat16* __restrict__ v) {
  __shared__ __hip_bfloat16 Xs[32 * XS2];   // 16896 B
  const int t = threadIdx.x;
  const int b = blockIdx.y, n0 = blockIdx.x * 32;
  const int w = __builtin_amdgcn_readfirstlane(t >> 6);
  const int ln = t & 15, quad = (t & 63) >> 4;
  const int sn = t & 31, scg = t >> 5;

  const float* xsrc = x + (size_t)b * NC * NN + n0 + sn;
#pragma unroll
  for (int g = 0; g < 4; ++g) {
    float xr[8];
#pragma unroll
    for (int i = 0; i < 8; ++i)
      xr[i] = xsrc[(size_t)(g * 64 + scg * 8 + i) * NN];
    uint4 pw;
    pw.x = pk2bf(xr[0], xr[1]);
    pw.y = pk2bf(xr[2], xr[3]);
    pw.z = pk2bf(xr[4], xr[5]);
    pw.w = pk2bf(xr[6], xr[7]);
    *(uint4*)&Xs[sn * XS2 + g * 64 + scg * 8] = pw;
  }
  __syncthreads();

  f32x4 zero4 = {0.f, 0.f, 0.f, 0.f};
  f32x4 acc[5][2];
#pragma unroll
  for (int i = 0; i < 5; ++i)
#pragma unroll
    for (int j = 0; j < 2; ++j) acc[i][j] = zero4;

  const __hip_bfloat16* wbase = W16 + (size_t)(w * 80 + ln) * NC + quad * 8;
  short8 afc[5], afn[5];
#pragma unroll
  for (int ot = 0; ot < 5; ++ot)
    afc[ot] = *(const short8*)(wbase + (size_t)ot * 16 * NC);

#pragma unroll 1
  for (int k0 = 0; k0 < NC; k0 += 32) {
    const int kn = k0 + 32;
    if (kn < NC) {
#pragma unroll
      for (int ot = 0; ot < 5; ++ot)
        afn[ot] = *(const short8*)(wbase + (size_t)ot * 16 * NC + kn);
    }
    short8 bfr[2];
#pragma unroll
    for (int nt = 0; nt < 2; ++nt)
      bfr[nt] = *(const short8*)&Xs[(nt * 16 + ln) * XS2 + k0 + quad * 8];
#pragma unroll
    for (int ot = 0; ot < 5; ++ot)
#pragma unroll
      for (int nt = 0; nt < 2; ++nt)
        acc[ot][nt] = MFMA16(afc[ot], bfr[nt], acc[ot][nt]);
#pragma unroll
    for (int ot = 0; ot < 5; ++ot) afc[ot] = afn[ot];
  }

#pragma unroll
  for (int ot = 0; ot < 5; ++ot) {
    const int gbase = w * 80 + ot * 16;
    if (gbase < 32) {
#pragma unroll
      for (int nt = 0; nt < 2; ++nt)
#pragma unroll
        for (int r = 0; r < 4; ++r) {
          const int row = gbase + quad * 4 + r;
          q[((size_t)b * NN + n0 + nt * 16 + ln) * DQK + row] =
              __hip_bfloat16(acc[ot][nt][r] + bq[row]);
        }
    } else if (gbase < 64) {
#pragma unroll
      for (int nt = 0; nt < 2; ++nt)
#pragma unroll
        for (int r = 0; r < 4; ++r) {
          const int row = gbase - 32 + quad * 4 + r;
          kT[((size_t)b * NN + n0 + nt * 16 + ln) * DQK + row] =
              __hip_bfloat16(acc[ot][nt][r] + bk[row]);
        }
    } else {
#pragma unroll
      for (int nt = 0; nt < 2; ++nt)
#pragma unroll
        for (int r = 0; r < 4; ++r) {
          const int c = gbase - 64 + quad * 4 + r;
          v[((size_t)b * NC + c) * NN + n0 + nt * 16 + ln] =
              __hip_bfloat16(acc[ot][nt][r] + bv[c]);
        }
    }
  }
}

// ---- DECOUPLED flash: 16 independent waves = 4 m-tiles x 4 c-quarters.
// Each wave: QK^T (swapped, mfma(K,Q)) -> exp -> P stays IN REGISTERS as the
// PV B-operand via a k-axis permutation applied to BOTH PV operands
// (pi(quad*8+e) = ks*32+(e>>2)*16+quad*4+(e&3); contraction is permutation-
// invariant). No P LDS, no producer/consumer barrier chain — the only barrier
// is the K/V staging dbuf sync, once per iter. QK duplicated 4x (+33% MFMA,
// the price of full wave independence).
__global__ __launch_bounds__(1024, 4) void flash_kernel(
    const __hip_bfloat16* __restrict__ q, const __hip_bfloat16* __restrict__ kt,
    const __hip_bfloat16* __restrict__ v, const float* __restrict__ x,
    const float* __restrict__ gamma, float* __restrict__ out) {
  __shared__ __align__(16) __hip_bfloat16 Ks[2][JT * DQK];    // 8 KB
  __shared__ __align__(16) __hip_bfloat16 Vs[2][NC * JT];     // 64 KB

  const int t  = threadIdx.x;
  const int bi = blockIdx.x;
  // XCD swizzle: XCD pair {2b,2b+1} serves batch b -> K/V slices stay L2-local
  const int b  = (bi & 7) >> 1;
  const int m0 = (((bi & 1) * 32) + (bi >> 3)) * MT;

  const int w    = __builtin_amdgcn_readfirstlane(t >> 6);   // 0..15
  const int l    = t & 63;
  const int ln   = t & 15;
  const int quad = (t & 63) >> 4;
  const int mt_  = w & 3;    // m-tile (16 rows)
  const int cq   = w >> 2;   // c-quarter (64 channels)

  const __hip_bfloat16* kb_base = kt + (size_t)b * NN * DQK;
  const __hip_bfloat16* v_base  = v + (size_t)b * NC * NN;

  // V stage: wave w covers granules g = w*2+k (8 c-rows x 64 j each), XOR-
  // swizzled source so LDS physical 16B-chunk p of row c holds j-chunk p^(c&7).
  size_t voff[2];
#pragma unroll
  for (int k = 0; k < 2; ++k) {
    const int g = w * 2 + k;
    voff[k] = (size_t)(g * 8 + (l >> 3)) * NN + (((l & 7) ^ ((l >> 3) & 7)) * 8);
  }
  // K stage (waves 0-3): granule w = 16 j-rows x 32 d, chunk x^(r&3) swizzle.
  const size_t koff = (size_t)(w * 16 + (l >> 2)) * DQK +
                      (((l & 3) ^ ((l >> 2) & 3)) * 8);

  // prologue: stage V(0), K(0)
#pragma unroll
  for (int k = 0; k < 2; ++k)
    gl16(v_base + voff[k], &Vs[0][(w * 2 + k) * 512]);
  if (w < 4) gl16(kb_base + koff, &Ks[0][w * 512]);
  __syncthreads();

  const short8 qa =
      *(const short8*)(q + ((size_t)b * NN + m0 + mt_ * 16 + ln) * DQK + quad * 8);
  const f32x4 zero4 = {0.f, 0.f, 0.f, 0.f};
  float lreg = 0.f;
  f32x4 acc[4];   // [ct]: rows c = cq*64+ct*16+quad*4+r, cols m = mt_*16+ln
#pragma unroll
  for (int ct = 0; ct < 4; ++ct) acc[ct] = zero4;

  for (int it = 0; it < NIT; ++it) {
    const int buf = it & 1;
    // stage next tile (drained by this iter's end barrier — full-iter cover)
    if (it + 1 < NIT) {
#pragma unroll
      for (int k = 0; k < 2; ++k)
        gl16(v_base + voff[k] + (size_t)(it + 1) * JT, &Vs[buf ^ 1][(w * 2 + k) * 512]);
      if (w < 4)
        gl16(kb_base + koff + (size_t)(it + 1) * JT * DQK, &Ks[buf ^ 1][w * 512]);
    }

    // K fragments from swizzled LDS
    short8 kb[4];
#pragma unroll
    for (int jt = 0; jt < 4; ++jt)
      kb[jt] = *(const short8*)&Ks[buf][(jt * 16 + ln) * DQK + ((quad ^ (ln & 3)) * 8)];

    // S^T: lane(ln,quad) holds S[m=ln][j = jt*16 + quad*4 + r]
    f32x4 st[4];
    __builtin_amdgcn_s_setprio(1);
#pragma unroll
    for (int jt = 0; jt < 4; ++jt) st[jt] = MFMA16(kb[jt], qa, zero4);
    __builtin_amdgcn_s_setprio(0);

    // P = exp(S), packed lane-locally; pf[ks] k-slot quad*8+e holds
    // P[m=ln][pi] with pi = ks*32+(e>>2)*16+quad*4+(e&3)  (zero shuffles)
    unsigned pkk[4][2];
#pragma unroll
    for (int jt = 0; jt < 4; ++jt) {
      const float e0 = __expf(st[jt][0]), e1 = __expf(st[jt][1]);
      const float e2 = __expf(st[jt][2]), e3 = __expf(st[jt][3]);
      lreg += (e0 + e1) + (e2 + e3);
      pkk[jt][0] = pk2bf(e0, e1);
      pkk[jt][1] = pk2bf(e2, e3);
    }
    short8 pf[2];
#pragma unroll
    for (int ks = 0; ks < 2; ++ks) {
      union { unsigned u[4]; short8 s; } cv;
      cv.u[0] = pkk[2 * ks][0];
      cv.u[1] = pkk[2 * ks][1];
      cv.u[2] = pkk[2 * ks + 1][0];
      cv.u[3] = pkk[2 * ks + 1][1];
      pf[ks] = cv.s;
    }

    // PV: va loaded with the SAME k-permutation (two b64s per fragment)
    const char* vb = (const char*)&Vs[buf][0];
#pragma unroll
    for (int ct = 0; ct < 4; ++ct) {
      const int c = cq * 64 + ct * 16 + ln;
      const char* vr = vb + (size_t)c * 128;
#pragma unroll
      for (int ks = 0; ks < 2; ++ks) {
        const int lcl = 4 * ks + (quad >> 1);        // j-chunk of e=0..3
        const int lch = lcl + 2;                     // j-chunk of e=4..7
        const int half = (quad & 1) * 8;
        union { short4v h[2]; short8 s; } vv;
        vv.h[0] = *(const short4v*)(vr + ((lcl ^ (ln & 7)) * 16 + half));
        vv.h[1] = *(const short4v*)(vr + ((lch ^ (ln & 7)) * 16 + half));
        __builtin_amdgcn_s_setprio(1);
        acc[ct] = MFMA16(vv.s, pf[ks], acc[ct]);
        __builtin_amdgcn_s_setprio(0);
      }
    }
    __syncthreads();
  }

  // l[m=ln]: reduce the per-quad j-subsets
  lreg += __shfl_xor(lreg, 16);
  lreg += __shfl_xor(lreg, 32);
  const float li = 1.f / lreg;

  // epilogue: out[b][c][m] = gamma*(O/l) + x ; O cols = m = lane ln (coalesced)
  const float g0 = gamma[0];
#pragma unroll
  for (int ct = 0; ct < 4; ++ct)
#pragma unroll
    for (int r = 0; r < 4; ++r) {
      const int c = cq * 64 + ct * 16 + quad * 4 + r;
      const size_t base = ((size_t)b * NC + c) * NN + m0 + mt_ * 16;
      out[base + ln] = g0 * (acc[ct][r] * li) + x[base + ln];
    }
}

extern "C" void kernel_launch(void* const* d_in, const int* in_sizes, int n_in,
                              void* d_out, int out_size, void* d_ws, size_t ws_size,
                              hipStream_t stream) {
  const float* x     = (const float*)d_in[0];
  const float* Wq    = (const float*)d_in[1];
  const float* bq    = (const float*)d_in[2];
  const float* Wk    = (const float*)d_in[3];
  const float* bk    = (const float*)d_in[4];
  const float* Wv    = (const float*)d_in[5];
  const float* bv    = (const float*)d_in[6];
  const float* gamma = (const float*)d_in[7];
  float* out = (float*)d_out;

  char* wsp = (char*)d_ws;
  __hip_bfloat16* W16 = (__hip_bfloat16*)wsp;  wsp += (size_t)320 * NC * 2;
  __hip_bfloat16* q   = (__hip_bfloat16*)wsp;  wsp += (size_t)NB * NN * DQK * 2;
  __hip_bfloat16* kT  = (__hip_bfloat16*)wsp;  wsp += (size_t)NB * NN * DQK * 2;
  __hip_bfloat16* v   = (__hip_bfloat16*)wsp;  // + 8.4 MB => ~10.6 MB total

  wcvt_kernel<<<dim3(80), dim3(256), 0, stream>>>(Wq, Wk, Wv, W16);
  proj_kernel<<<dim3(NN / 32, NB), dim3(256), 0, stream>>>(x, W16, bq, bk, bv, q, kT, v);
  flash_kernel<<<dim3(NB * NN / MT), dim3(1024), 0, stream>>>(q, kT, v, x, gamma, out);
}

// Round 11
// 178.436 us; speedup vs baseline: 1.0118x; 1.0118x over previous
//
#include <hip/hip_runtime.h>
#include <hip/hip_bf16.h>
#include <cstddef>

#define NB  4
#define NC  256
#define NN  4096
#define DQK 32
#define MT  64       // query rows per flash block
#define JT  64       // key tile per iteration
#define NIT (NN / JT)
#define XS2 264      // proj LDS row stride in bf16 ([32 n][256 c] + 8 pad)

typedef __attribute__((ext_vector_type(8))) short short8;
typedef __attribute__((ext_vector_type(4))) float f32x4;

#define MFMA16(a, b, c) __builtin_amdgcn_mfma_f32_16x16x32_bf16((a), (b), (c), 0, 0, 0)

__device__ inline unsigned pk2bf(float a, float b) {
  __hip_bfloat162 h = __float22bfloat162_rn(make_float2(a, b));
  unsigned u;
  __builtin_memcpy(&u, &h, 4);
  return u;
}

// async global->LDS, 16B per lane; LDS dest = uniform base + lane*16 (linear),
// global src is per-lane (pre-swizzled to realize the XOR'd LDS layout).
__device__ inline void gl16(const void* g, void* s) {
  __builtin_amdgcn_global_load_lds(
      (const __attribute__((address_space(1))) void*)g,
      (__attribute__((address_space(3))) void*)s, 16, 0, 0);
}

// ---- W convert: [Wq(32);Wk(32);Wv(256)] f32 -> W16[320][256] bf16 ----
__global__ __launch_bounds__(256) void wcvt_kernel(
    const float* __restrict__ Wq, const float* __restrict__ Wk,
    const float* __restrict__ Wv, __hip_bfloat16* __restrict__ W16) {
  const int id4 = (blockIdx.x * 256 + threadIdx.x) * 4;   // 80 blocks -> 81920
  const int row = id4 >> 8, col = id4 & 255;
  const float* src = (row < 32) ? Wq + row * 256
                   : (row < 64) ? Wk + (row - 32) * 256
                                : Wv + (row - 64) * 256;
  float4 vv = *(const float4*)(src + col);
  *(uint2*)(W16 + id4) = make_uint2(pk2bf(vv.x, vv.y), pk2bf(vv.z, vv.w));
}

// ---- fused proj (unchanged, rolled k-loop) ----
__global__ __launch_bounds__(256, 4) void proj_kernel(
    const float* __restrict__ x, const __hip_bfloat16* __restrict__ W16,
    const float* __restrict__ bq, const float* __restrict__ bk,
    const float* __restrict__ bv, __hip_bfloat16* __restrict__ q,
    __hip_bfloat16* __restrict__ kT, __hip_bfloat16* __restrict__ v) {
  __shared__ __hip_bfloat16 Xs[32 * XS2];   // 16896 B
  const int t = threadIdx.x;
  const int b = blockIdx.y, n0 = blockIdx.x * 32;
  const int w = __builtin_amdgcn_readfirstlane(t >> 6);
  const int ln = t & 15, quad = (t & 63) >> 4;
  const int sn = t & 31, scg = t >> 5;

  const float* xsrc = x + (size_t)b * NC * NN + n0 + sn;
#pragma unroll
  for (int g = 0; g < 4; ++g) {
    float xr[8];
#pragma unroll
    for (int i = 0; i < 8; ++i)
      xr[i] = xsrc[(size_t)(g * 64 + scg * 8 + i) * NN];
    uint4 pw;
    pw.x = pk2bf(xr[0], xr[1]);
    pw.y = pk2bf(xr[2], xr[3]);
    pw.z = pk2bf(xr[4], xr[5]);
    pw.w = pk2bf(xr[6], xr[7]);
    *(uint4*)&Xs[sn * XS2 + g * 64 + scg * 8] = pw;
  }
  __syncthreads();

  f32x4 zero4 = {0.f, 0.f, 0.f, 0.f};
  f32x4 acc[5][2];
#pragma unroll
  for (int i = 0; i < 5; ++i)
#pragma unroll
    for (int j = 0; j < 2; ++j) acc[i][j] = zero4;

  const __hip_bfloat16* wbase = W16 + (size_t)(w * 80 + ln) * NC + quad * 8;
  short8 afc[5], afn[5];
#pragma unroll
  for (int ot = 0; ot < 5; ++ot)
    afc[ot] = *(const short8*)(wbase + (size_t)ot * 16 * NC);

#pragma unroll 1
  for (int k0 = 0; k0 < NC; k0 += 32) {
    const int kn = k0 + 32;
    if (kn < NC) {
#pragma unroll
      for (int ot = 0; ot < 5; ++ot)
        afn[ot] = *(const short8*)(wbase + (size_t)ot * 16 * NC + kn);
    }
    short8 bfr[2];
#pragma unroll
    for (int nt = 0; nt < 2; ++nt)
      bfr[nt] = *(const short8*)&Xs[(nt * 16 + ln) * XS2 + k0 + quad * 8];
#pragma unroll
    for (int ot = 0; ot < 5; ++ot)
#pragma unroll
      for (int nt = 0; nt < 2; ++nt)
        acc[ot][nt] = MFMA16(afc[ot], bfr[nt], acc[ot][nt]);
#pragma unroll
    for (int ot = 0; ot < 5; ++ot) afc[ot] = afn[ot];
  }

#pragma unroll
  for (int ot = 0; ot < 5; ++ot) {
    const int gbase = w * 80 + ot * 16;
    if (gbase < 32) {
#pragma unroll
      for (int nt = 0; nt < 2; ++nt)
#pragma unroll
        for (int r = 0; r < 4; ++r) {
          const int row = gbase + quad * 4 + r;
          q[((size_t)b * NN + n0 + nt * 16 + ln) * DQK + row] =
              __hip_bfloat16(acc[ot][nt][r] + bq[row]);
        }
    } else if (gbase < 64) {
#pragma unroll
      for (int nt = 0; nt < 2; ++nt)
#pragma unroll
        for (int r = 0; r < 4; ++r) {
          const int row = gbase - 32 + quad * 4 + r;
          kT[((size_t)b * NN + n0 + nt * 16 + ln) * DQK + row] =
              __hip_bfloat16(acc[ot][nt][r] + bk[row]);
        }
    } else {
#pragma unroll
      for (int nt = 0; nt < 2; ++nt)
#pragma unroll
        for (int r = 0; r < 4; ++r) {
          const int c = gbase - 64 + quad * 4 + r;
          v[((size_t)b * NC + c) * NN + n0 + nt * 16 + ln] =
              __hip_bfloat16(acc[ot][nt][r] + bv[c]);
        }
    }
  }
}

// ---- pipelined wave-specialized flash ----
// V: TRIPLE-buffered LDS (stage it+1, read it-1: ~2 windows of DMA cover).
// K: producer registers, ping-pong prefetch (no K LDS traffic).
// Barriers: raw s_barrier with counted per-role vmcnt (prod 8, cons 4) —
// stages stay in flight across barriers; each wave verifies its own previous
// stages pre-barrier so cross-wave reads see landed data.
// j-axis row-permutation rho(jt*16+quad*4+r) = quad*16+jt*4+r applied at K
// staging: each lane's P/V j-set = 16 contiguous j -> V and P fragment reads
// are single b128 at per-quad-distinct chunks (bank-uniform), P write = 2 b128.
__global__ __launch_bounds__(512, 2) void flash_kernel(
    const __hip_bfloat16* __restrict__ q, const __hip_bfloat16* __restrict__ kt,
    const __hip_bfloat16* __restrict__ v, const float* __restrict__ x,
    const float* __restrict__ gamma, float* __restrict__ out) {
  __shared__ __align__(16) __hip_bfloat16 Vs[3][NC * JT];   // 96 KB
  __shared__ __align__(16) __hip_bfloat16 Ps[2][MT * JT];   // 16 KB
  __shared__ float lrow[MT];

  const int t  = threadIdx.x;
  const int bi = blockIdx.x;
  // XCD swizzle: XCD pair {2b,2b+1} serves batch b -> K/V slices stay L2-local
  const int b  = (bi & 7) >> 1;
  const int m0 = (((bi & 1) * 32) + (bi >> 3)) * MT;

  const int w    = __builtin_amdgcn_readfirstlane(t >> 6);   // 0..7
  const int l    = t & 63;
  const int ln   = t & 15;
  const int quad = (t & 63) >> 4;

  const __hip_bfloat16* kb_base = kt + (size_t)b * NN * DQK;
  const __hip_bfloat16* v_base  = v + (size_t)b * NC * NN;

  // V stage: wave w owns granules w*4+k (8 c-rows x 64 j, 1KB). Source XOR-
  // swizzled so phys 16B-chunk p of row c holds j-chunk p^(c&7).
  size_t voff[4];
#pragma unroll
  for (int k = 0; k < 4; ++k)
    voff[k] = (size_t)((w * 4 + k) * 8 + (l >> 3)) * NN +
              (((l & 7) ^ ((l >> 3) & 7)) * 8);

  // byte offsets of this lane's two j-chunks (ks=0,1) in a 128B P/V row
  const int swz0 = (((2 * quad + 0) ^ (ln & 7)) * 16);
  const int swz1 = (((2 * quad + 1) ^ (ln & 7)) * 16);

  // prologue: stage V(0) into Vs[0]
#pragma unroll
  for (int k = 0; k < 4; ++k)
    gl16(v_base + voff[k], &Vs[0][(w * 4 + k) * 512]);

  if (w < 4) {
    // ---------------- producer: rows m = m0 + w*16 + ln ----------------
    const short8 qa =
        *(const short8*)(q + ((size_t)b * NN + m0 + w * 16 + ln) * DQK + quad * 8);
    const int rp = ((ln >> 2) & 3) * 16 + (ln & 3);   // rho row gather base
    const f32x4 zero4 = {0.f, 0.f, 0.f, 0.f};
    float lreg = 0.f;
    const int m = w * 16 + ln;
    char* const prow0 = (char*)&Ps[0][0] + m * 128;
    char* const prow1 = (char*)&Ps[1][0] + m * 128;
    short8 kb0[4], kb1[4];
#pragma unroll
    for (int jt = 0; jt < 4; ++jt)
      kb0[jt] = *(const short8*)(kb_base + (size_t)(rp + jt * 4) * DQK + quad * 8);
    int sb = 1;

#define PROD_STEP(IT, KBC, KBN, PROW)                                          \
  do {                                                                         \
    if ((IT) + 1 < NIT) {                                                      \
      const size_t jn = (size_t)((IT) + 1) * JT;                               \
      _Pragma("unroll") for (int k = 0; k < 4; ++k)                            \
          gl16(v_base + voff[k] + jn, &Vs[sb][(w * 4 + k) * 512]);             \
      _Pragma("unroll") for (int jt = 0; jt < 4; ++jt)                         \
          KBN[jt] = *(const short8*)(kb_base + (jn + rp + jt * 4) * DQK +      \
                                     quad * 8);                                \
      asm volatile("s_waitcnt vmcnt(8)" ::: "memory");                         \
    } else {                                                                   \
      asm volatile("s_waitcnt vmcnt(0)" ::: "memory");                         \
    }                                                                          \
    f32x4 st[4];                                                               \
    __builtin_amdgcn_s_setprio(1);                                             \
    _Pragma("unroll") for (int jt = 0; jt < 4; ++jt)                           \
        st[jt] = MFMA16(KBC[jt], qa, zero4);                                   \
    __builtin_amdgcn_s_setprio(0);                                             \
    unsigned pkk[4][2];                                                        \
    _Pragma("unroll") for (int jt = 0; jt < 4; ++jt) {                         \
      const float e0 = __expf(st[jt][0]), e1 = __expf(st[jt][1]);              \
      const float e2 = __expf(st[jt][2]), e3 = __expf(st[jt][3]);              \
      lreg += (e0 + e1) + (e2 + e3);                                           \
      pkk[jt][0] = pk2bf(e0, e1);                                              \
      pkk[jt][1] = pk2bf(e2, e3);                                              \
    }                                                                          \
    _Pragma("unroll") for (int ks = 0; ks < 2; ++ks) {                         \
      union { unsigned u[4]; short8 s; } cv;                                   \
      cv.u[0] = pkk[2 * ks][0];                                                \
      cv.u[1] = pkk[2 * ks][1];                                                \
      cv.u[2] = pkk[2 * ks + 1][0];                                            \
      cv.u[3] = pkk[2 * ks + 1][1];                                            \
      *(short8*)((PROW) + (ks ? swz1 : swz0)) = cv.s;                          \
    }                                                                          \
    sb = (sb == 2) ? 0 : sb + 1;                                               \
    asm volatile("s_waitcnt lgkmcnt(0)" ::: "memory");                         \
    __builtin_amdgcn_s_barrier();                                              \
    asm volatile("" ::: "memory");                                             \
  } while (0)

    for (int it = 0; it < NIT; it += 2) {
      PROD_STEP(it, kb0, kb1, prow0);
      PROD_STEP(it + 1, kb1, kb0, prow1);
    }
#undef PROD_STEP
    // l: quads hold disjoint 16-j subsets per iter
    lreg += __shfl_xor(lreg, 16);
    lreg += __shfl_xor(lreg, 32);
    if (quad == 0) lrow[m] = lreg;
    __syncthreads();   // barrier #(NIT+1)
  } else {
    // ---------------- consumer: channels [c0, c0+64), one iter behind ------
    const int c0 = (w - 4) * 64;
    const f32x4 zero4 = {0.f, 0.f, 0.f, 0.f};
    f32x4 acc[4][4];
#pragma unroll
    for (int ct = 0; ct < 4; ++ct)
#pragma unroll
      for (int mt = 0; mt < 4; ++mt) acc[ct][mt] = zero4;

    int sb = 1, rb = 2;   // rb tracks (it-1)%3
    for (int it = 0; it < NIT; ++it) {
      if (it + 1 < NIT) {
        const size_t jn = (size_t)(it + 1) * JT;
#pragma unroll
        for (int k = 0; k < 4; ++k)
          gl16(v_base + voff[k] + jn, &Vs[sb][(w * 4 + k) * 512]);
        asm volatile("s_waitcnt vmcnt(4)" ::: "memory");
      } else {
        asm volatile("s_waitcnt vmcnt(0)" ::: "memory");
      }
      if (it > 0) {
        const char* vbb = (const char*)&Vs[rb][0];
        const char* pbb = (const char*)&Ps[(it - 1) & 1][0];
        short8 va[4][2];
#pragma unroll
        for (int ct = 0; ct < 4; ++ct) {
          const char* vr = vbb + (size_t)(c0 + ct * 16 + ln) * 128;
          va[ct][0] = *(const short8*)(vr + swz0);
          va[ct][1] = *(const short8*)(vr + swz1);
        }
#pragma unroll
        for (int ks = 0; ks < 2; ++ks) {
          short8 pb[4];
#pragma unroll
          for (int mt = 0; mt < 4; ++mt)
            pb[mt] = *(const short8*)(pbb + (size_t)(mt * 16 + ln) * 128 +
                                      (ks ? swz1 : swz0));
          __builtin_amdgcn_s_setprio(1);
#pragma unroll
          for (int ct = 0; ct < 4; ++ct)
#pragma unroll
            for (int mt = 0; mt < 4; ++mt)
              acc[ct][mt] = MFMA16(va[ct][ks], pb[mt], acc[ct][mt]);
          __builtin_amdgcn_s_setprio(0);
        }
      }
      sb = (sb == 2) ? 0 : sb + 1;
      rb = (rb == 2) ? 0 : rb + 1;
      asm volatile("s_waitcnt lgkmcnt(0)" ::: "memory");
      __builtin_amdgcn_s_barrier();
      asm volatile("" ::: "memory");
    }
    // final tile NIT-1 (rb == (NIT-1)%3 after the loop)
    {
      const char* vbb = (const char*)&Vs[rb][0];
      const char* pbb = (const char*)&Ps[(NIT - 1) & 1][0];
      short8 va[4][2];
#pragma unroll
      for (int ct = 0; ct < 4; ++ct) {
        const char* vr = vbb + (size_t)(c0 + ct * 16 + ln) * 128;
        va[ct][0] = *(const short8*)(vr + swz0);
        va[ct][1] = *(const short8*)(vr + swz1);
      }
#pragma unroll
      for (int ks = 0; ks < 2; ++ks) {
        short8 pb[4];
#pragma unroll
        for (int mt = 0; mt < 4; ++mt)
          pb[mt] = *(const short8*)(pbb + (size_t)(mt * 16 + ln) * 128 +
                                    (ks ? swz1 : swz0));
        __builtin_amdgcn_s_setprio(1);
#pragma unroll
        for (int ct = 0; ct < 4; ++ct)
#pragma unroll
          for (int mt = 0; mt < 4; ++mt)
            acc[ct][mt] = MFMA16(va[ct][ks], pb[mt], acc[ct][mt]);
        __builtin_amdgcn_s_setprio(0);
      }
    }
    __syncthreads();   // barrier #(NIT+1): lrow visible

    // epilogue: out[b][c][m] = gamma*(O'/l) + x
    const float g0 = gamma[0];
    float li[4];
#pragma unroll
    for (int mt = 0; mt < 4; ++mt) li[mt] = 1.f / lrow[mt * 16 + ln];
#pragma unroll
    for (int ct = 0; ct < 4; ++ct)
#pragma unroll
      for (int r = 0; r < 4; ++r) {
        const int c = c0 + ct * 16 + quad * 4 + r;
        const float* xr = x + ((size_t)b * NC + c) * NN + m0;
        float* orow = out + ((size_t)b * NC + c) * NN + m0;
#pragma unroll
        for (int mt = 0; mt < 4; ++mt) {
          const int m = mt * 16 + ln;
          orow[m] = g0 * (acc[ct][mt][r] * li[mt]) + xr[m];
        }
      }
  }
}

extern "C" void kernel_launch(void* const* d_in, const int* in_sizes, int n_in,
                              void* d_out, int out_size, void* d_ws, size_t ws_size,
                              hipStream_t stream) {
  const float* x     = (const float*)d_in[0];
  const float* Wq    = (const float*)d_in[1];
  const float* bq    = (const float*)d_in[2];
  const float* Wk    = (const float*)d_in[3];
  const float* bk    = (const float*)d_in[4];
  const float* Wv    = (const float*)d_in[5];
  const float* bv    = (const float*)d_in[6];
  const float* gamma = (const float*)d_in[7];
  float* out = (float*)d_out;

  char* wsp = (char*)d_ws;
  __hip_bfloat16* W16 = (__hip_bfloat16*)wsp;  wsp += (size_t)320 * NC * 2;
  __hip_bfloat16* q   = (__hip_bfloat16*)wsp;  wsp += (size_t)NB * NN * DQK * 2;
  __hip_bfloat16* kT  = (__hip_bfloat16*)wsp;  wsp += (size_t)NB * NN * DQK * 2;
  __hip_bfloat16* v   = (__hip_bfloat16*)wsp;  // + 8.4 MB => ~10.6 MB total

  wcvt_kernel<<<dim3(80), dim3(256), 0, stream>>>(Wq, Wk, Wv, W16);
  proj_kernel<<<dim3(NN / 32, NB), dim3(256), 0, stream>>>(x, W16, bq, bk, bv, q, kT, v);
  flash_kernel<<<dim3(NB * NN / MT), dim3(512), 0, stream>>>(q, kT, v, x, gamma, out);
}

// Round 12
// 162.669 us; speedup vs baseline: 1.1098x; 1.0969x over previous
//
#include <hip/hip_runtime.h>
#include <hip/hip_bf16.h>
#include <cstddef>

#define NB  4
#define NC  256
#define NN  4096
#define DQK 32
#define MT  64       // query rows per flash block
#define JT  64       // key tile per iteration
#define NIT (NN / JT)
#define XS2 264      // proj LDS row stride in bf16 ([32 n][256 c] + 8 pad)

typedef __attribute__((ext_vector_type(8))) short short8;
typedef __attribute__((ext_vector_type(4))) float f32x4;

#define MFMA16(a, b, c) __builtin_amdgcn_mfma_f32_16x16x32_bf16((a), (b), (c), 0, 0, 0)

__device__ inline unsigned pk2bf(float a, float b) {
  __hip_bfloat162 h = __float22bfloat162_rn(make_float2(a, b));
  unsigned u;
  __builtin_memcpy(&u, &h, 4);
  return u;
}

// async global->LDS, 16B per lane; LDS dest = uniform base + lane*16 (linear),
// global src is per-lane (pre-swizzled to realize the XOR'd LDS layout).
__device__ inline void gl16(const void* g, void* s) {
  __builtin_amdgcn_global_load_lds(
      (const __attribute__((address_space(1))) void*)g,
      (__attribute__((address_space(3))) void*)s, 16, 0, 0);
}

// fenced barrier with counted vmcnt: stages stay in flight across the barrier
// (never drain to 0 mid-loop); lgkmcnt(0) publishes LDS writes; trailing
// clobber stops LLVM hoisting post-barrier LDS reads (round-5 race).
template <int N>
__device__ inline void bar_vm() {
  asm volatile("s_waitcnt lgkmcnt(0)" ::: "memory");
  asm volatile("s_waitcnt vmcnt(%0)" ::"n"(N) : "memory");
  __builtin_amdgcn_s_barrier();
  asm volatile("" ::: "memory");
}

// ---- W convert: [Wq(32);Wk(32);Wv(256)] f32 -> W16[320][256] bf16 ----
__global__ __launch_bounds__(256) void wcvt_kernel(
    const float* __restrict__ Wq, const float* __restrict__ Wk,
    const float* __restrict__ Wv, __hip_bfloat16* __restrict__ W16) {
  const int id4 = (blockIdx.x * 256 + threadIdx.x) * 4;   // 80 blocks -> 81920
  const int row = id4 >> 8, col = id4 & 255;
  const float* src = (row < 32) ? Wq + row * 256
                   : (row < 64) ? Wk + (row - 32) * 256
                                : Wv + (row - 64) * 256;
  float4 vv = *(const float4*)(src + col);
  *(uint2*)(W16 + id4) = make_uint2(pk2bf(vv.x, vv.y), pk2bf(vv.z, vv.w));
}

// ---- fused proj (unchanged, rolled k-loop) ----
__global__ __launch_bounds__(256, 4) void proj_kernel(
    const float* __restrict__ x, const __hip_bfloat16* __restrict__ W16,
    const float* __restrict__ bq, const float* __restrict__ bk,
    const float* __restrict__ bv, __hip_bfloat16* __restrict__ q,
    __hip_bfloat16* __restrict__ kT, __hip_bfloat16* __restrict__ v) {
  __shared__ __hip_bfloat16 Xs[32 * XS2];   // 16896 B
  const int t = threadIdx.x;
  const int b = blockIdx.y, n0 = blockIdx.x * 32;
  const int w = __builtin_amdgcn_readfirstlane(t >> 6);
  const int ln = t & 15, quad = (t & 63) >> 4;
  const int sn = t & 31, scg = t >> 5;

  const float* xsrc = x + (size_t)b * NC * NN + n0 + sn;
#pragma unroll
  for (int g = 0; g < 4; ++g) {
    float xr[8];
#pragma unroll
    for (int i = 0; i < 8; ++i)
      xr[i] = xsrc[(size_t)(g * 64 + scg * 8 + i) * NN];
    uint4 pw;
    pw.x = pk2bf(xr[0], xr[1]);
    pw.y = pk2bf(xr[2], xr[3]);
    pw.z = pk2bf(xr[4], xr[5]);
    pw.w = pk2bf(xr[6], xr[7]);
    *(uint4*)&Xs[sn * XS2 + g * 64 + scg * 8] = pw;
  }
  __syncthreads();

  f32x4 zero4 = {0.f, 0.f, 0.f, 0.f};
  f32x4 acc[5][2];
#pragma unroll
  for (int i = 0; i < 5; ++i)
#pragma unroll
    for (int j = 0; j < 2; ++j) acc[i][j] = zero4;

  const __hip_bfloat16* wbase = W16 + (size_t)(w * 80 + ln) * NC + quad * 8;
  short8 afc[5], afn[5];
#pragma unroll
  for (int ot = 0; ot < 5; ++ot)
    afc[ot] = *(const short8*)(wbase + (size_t)ot * 16 * NC);

#pragma unroll 1
  for (int k0 = 0; k0 < NC; k0 += 32) {
    const int kn = k0 + 32;
    if (kn < NC) {
#pragma unroll
      for (int ot = 0; ot < 5; ++ot)
        afn[ot] = *(const short8*)(wbase + (size_t)ot * 16 * NC + kn);
    }
    short8 bfr[2];
#pragma unroll
    for (int nt = 0; nt < 2; ++nt)
      bfr[nt] = *(const short8*)&Xs[(nt * 16 + ln) * XS2 + k0 + quad * 8];
#pragma unroll
    for (int ot = 0; ot < 5; ++ot)
#pragma unroll
      for (int nt = 0; nt < 2; ++nt)
        acc[ot][nt] = MFMA16(afc[ot], bfr[nt], acc[ot][nt]);
#pragma unroll
    for (int ot = 0; ot < 5; ++ot) afc[ot] = afn[ot];
  }

#pragma unroll
  for (int ot = 0; ot < 5; ++ot) {
    const int gbase = w * 80 + ot * 16;
    if (gbase < 32) {
#pragma unroll
      for (int nt = 0; nt < 2; ++nt)
#pragma unroll
        for (int r = 0; r < 4; ++r) {
          const int row = gbase + quad * 4 + r;
          q[((size_t)b * NN + n0 + nt * 16 + ln) * DQK + row] =
              __hip_bfloat16(acc[ot][nt][r] + bq[row]);
        }
    } else if (gbase < 64) {
#pragma unroll
      for (int nt = 0; nt < 2; ++nt)
#pragma unroll
        for (int r = 0; r < 4; ++r) {
          const int row = gbase - 32 + quad * 4 + r;
          kT[((size_t)b * NN + n0 + nt * 16 + ln) * DQK + row] =
              __hip_bfloat16(acc[ot][nt][r] + bk[row]);
        }
    } else {
#pragma unroll
      for (int nt = 0; nt < 2; ++nt)
#pragma unroll
        for (int r = 0; r < 4; ++r) {
          const int c = gbase - 64 + quad * 4 + r;
          v[((size_t)b * NC + c) * NN + n0 + nt * 16 + ln] =
              __hip_bfloat16(acc[ot][nt][r] + bv[c]);
        }
    }
  }
}

// ---- R8 flash + distance-2 pipeline (the ONLY change vs round 8/9):
// V quad-buffered, K triple-buffered; stage(it+2) issued at top of iter it;
// counted vmcnt (prod 5 / cons 8, tail 0) so DMA spans barriers instead of
// draining every iteration. Fragment swizzles / P handoff byte-identical R8.
__global__ __launch_bounds__(512, 2) void flash_kernel(
    const __hip_bfloat16* __restrict__ q, const __hip_bfloat16* __restrict__ kt,
    const __hip_bfloat16* __restrict__ v, const float* __restrict__ x,
    const float* __restrict__ gamma, float* __restrict__ out) {
  __shared__ __align__(16) __hip_bfloat16 Vs[4][NC * JT];   // 128 KB
  __shared__ __align__(16) __hip_bfloat16 Ks[3][JT * DQK];  // 12 KB
  __shared__ __align__(16) __hip_bfloat16 Ps[2][MT * JT];   // 16 KB
  __shared__ float lrow[MT];                                // 160000 B total

  const int t  = threadIdx.x;
  const int bi = blockIdx.x;
  // XCD swizzle: XCD pair {2b,2b+1} serves batch b -> K/V slices stay L2-local
  const int b  = (bi & 7) >> 1;
  const int m0 = (((bi & 1) * 32) + (bi >> 3)) * MT;

  const int w    = __builtin_amdgcn_readfirstlane(t >> 6);   // 0..7
  const int l    = t & 63;
  const int ln   = t & 15;
  const int quad = (t & 63) >> 4;

  const __hip_bfloat16* kb_base = kt + (size_t)b * NN * DQK;
  const __hip_bfloat16* v_base  = v + (size_t)b * NC * NN;

  // V stage: wave w owns granules w*4+k (8 c-rows x 64 j, 1KB each). Source
  // XOR-swizzled: physical 16B-chunk p of row c holds j-chunk p^(c&7).
  size_t voff[4];
#pragma unroll
  for (int k = 0; k < 4; ++k)
    voff[k] = (size_t)((w * 4 + k) * 8 + (l >> 3)) * NN +
              (((l & 7) ^ ((l >> 3) & 7)) * 8);
  // K stage (producers): granule w = 16 j-rows x 32 d; chunk p=l&3 holds
  // d-chunk p^(r&3).
  const size_t koff = (size_t)(w * 16 + (l >> 2)) * DQK +
                      (((l & 3) ^ ((l >> 2) & 3)) * 8);

  // prologue: stage(0) and stage(1)
#pragma unroll
  for (int j = 0; j < 2; ++j) {
#pragma unroll
    for (int k = 0; k < 4; ++k)
      gl16(v_base + voff[k] + (size_t)j * JT, &Vs[j][(w * 4 + k) * 512]);
    if (w < 4)
      gl16(kb_base + koff + (size_t)j * JT * DQK, &Ks[j][w * 512]);
  }

  if (w < 4) {
    // ---------------- producer: rows m = m0 + w*16 + ln ----------------
    bar_vm<5>();   // stage(0) landed (incl. K(0)); stage(1) in flight
    const short8 qa =
        *(const short8*)(q + ((size_t)b * NN + m0 + w * 16 + ln) * DQK + quad * 8);
    float lreg = 0.f;
    const f32x4 zero4 = {0.f, 0.f, 0.f, 0.f};
    const int m = w * 16 + ln;

    for (int it = 0; it < NIT; ++it) {
      const bool more = (it + 2 < NIT);
      if (more) {
        const size_t jn = (size_t)(it + 2) * JT;
#pragma unroll
        for (int k = 0; k < 4; ++k)
          gl16(v_base + voff[k] + jn, &Vs[(it + 2) & 3][(w * 4 + k) * 512]);
        gl16(kb_base + koff + jn * DQK, &Ks[(it + 2) % 3][w * 512]);
      }

      // K fragments from Ks[it%3] (staged 2 iters ago — resident)
      short8 kb[4];
#pragma unroll
      for (int jt = 0; jt < 4; ++jt)
        kb[jt] = *(const short8*)&Ks[it % 3][(jt * 16 + ln) * DQK +
                                             ((quad ^ (ln & 3)) * 8)];
      f32x4 st[4];
      __builtin_amdgcn_s_setprio(1);
#pragma unroll
      for (int jt = 0; jt < 4; ++jt) st[jt] = MFMA16(kb[jt], qa, zero4);
      __builtin_amdgcn_s_setprio(0);

      // P = exp(S); packed b64 swizzled writes (R8-verbatim)
      char* pbase = (char*)&Ps[it & 1][0] + m * (JT * 2);
#pragma unroll
      for (int jt = 0; jt < 4; ++jt) {
        const float e0 = __expf(st[jt][0]), e1 = __expf(st[jt][1]);
        const float e2 = __expf(st[jt][2]), e3 = __expf(st[jt][3]);
        lreg += (e0 + e1) + (e2 + e3);
        *(uint2*)(pbase + ((jt * 32 + quad * 8) ^ ((m & 7) << 4))) =
            make_uint2(pk2bf(e0, e1), pk2bf(e2, e3));
      }
      if (more) bar_vm<5>(); else bar_vm<0>();
    }
    // l: quads hold disjoint 16-j subsets per iter
    lreg += __shfl_xor(lreg, 16);
    lreg += __shfl_xor(lreg, 32);
    if (quad == 0) lrow[m] = lreg;
    __syncthreads();   // barrier #(NIT+2)
  } else {
    // ---------------- consumer: channels [c0, c0+64), one iter behind ------
    bar_vm<8>();   // own stage(0/1) may stay in flight (first read at it=1)
    const int c0 = (w - 4) * 64;
    const f32x4 zero4 = {0.f, 0.f, 0.f, 0.f};
    f32x4 acc[4][4];
#pragma unroll
    for (int ct = 0; ct < 4; ++ct)
#pragma unroll
      for (int mt = 0; mt < 4; ++mt) acc[ct][mt] = zero4;

    for (int it = 0; it < NIT; ++it) {
      const bool more = (it + 2 < NIT);
      if (more) {
        const size_t jn = (size_t)(it + 2) * JT;
#pragma unroll
        for (int k = 0; k < 4; ++k)
          gl16(v_base + voff[k] + jn, &Vs[(it + 2) & 3][(w * 4 + k) * 512]);
      }
      if (it > 0) {
        const char* vbb = (const char*)&Vs[(it - 1) & 3][0];
        const char* pbb = (const char*)&Ps[(it - 1) & 1][0];
        short8 va[4][2];
#pragma unroll
        for (int ct = 0; ct < 4; ++ct)
#pragma unroll
          for (int ks = 0; ks < 2; ++ks)
            va[ct][ks] = *(const short8*)(vbb +
                (size_t)(c0 + ct * 16 + ln) * (JT * 2) +
                (((ks * 4 + quad) ^ (ln & 7)) * 16));
#pragma unroll
        for (int ks = 0; ks < 2; ++ks) {
          short8 pb[4];
#pragma unroll
          for (int mt = 0; mt < 4; ++mt)
            pb[mt] = *(const short8*)(pbb + (size_t)(mt * 16 + ln) * (JT * 2) +
                                      ((ks * 64 + quad * 16) ^ ((ln & 7) << 4)));
          __builtin_amdgcn_s_setprio(1);
#pragma unroll
          for (int ct = 0; ct < 4; ++ct)
#pragma unroll
            for (int mt = 0; mt < 4; ++mt)
              acc[ct][mt] = MFMA16(va[ct][ks], pb[mt], acc[ct][mt]);
          __builtin_amdgcn_s_setprio(0);
        }
      }
      if (more) bar_vm<8>(); else bar_vm<0>();
    }

    // final tile NIT-1 (staged at NIT-3; published by barrier #NIT+1)
    {
      const char* vbb = (const char*)&Vs[(NIT - 1) & 3][0];
      const char* pbb = (const char*)&Ps[(NIT - 1) & 1][0];
      short8 va[4][2];
#pragma unroll
      for (int ct = 0; ct < 4; ++ct)
#pragma unroll
        for (int ks = 0; ks < 2; ++ks)
          va[ct][ks] = *(const short8*)(vbb +
              (size_t)(c0 + ct * 16 + ln) * (JT * 2) +
              (((ks * 4 + quad) ^ (ln & 7)) * 16));
#pragma unroll
      for (int ks = 0; ks < 2; ++ks) {
        short8 pb[4];
#pragma unroll
        for (int mt = 0; mt < 4; ++mt)
          pb[mt] = *(const short8*)(pbb + (size_t)(mt * 16 + ln) * (JT * 2) +
                                    ((ks * 64 + quad * 16) ^ ((ln & 7) << 4)));
        __builtin_amdgcn_s_setprio(1);
#pragma unroll
        for (int ct = 0; ct < 4; ++ct)
#pragma unroll
          for (int mt = 0; mt < 4; ++mt)
            acc[ct][mt] = MFMA16(va[ct][ks], pb[mt], acc[ct][mt]);
        __builtin_amdgcn_s_setprio(0);
      }
    }
    __syncthreads();   // barrier #(NIT+2): lrow visible

    // epilogue: out[b][c][m] = gamma*(O'/l) + x
    const float g0 = gamma[0];
    float li[4];
#pragma unroll
    for (int mt = 0; mt < 4; ++mt) li[mt] = 1.f / lrow[mt * 16 + ln];
#pragma unroll
    for (int ct = 0; ct < 4; ++ct)
#pragma unroll
      for (int r = 0; r < 4; ++r) {
        const int c = c0 + ct * 16 + quad * 4 + r;
        const float* xr = x + ((size_t)b * NC + c) * NN + m0;
        float* orow = out + ((size_t)b * NC + c) * NN + m0;
#pragma unroll
        for (int mt = 0; mt < 4; ++mt) {
          const int m = mt * 16 + ln;
          orow[m] = g0 * (acc[ct][mt][r] * li[mt]) + xr[m];
        }
      }
  }
}

extern "C" void kernel_launch(void* const* d_in, const int* in_sizes, int n_in,
                              void* d_out, int out_size, void* d_ws, size_t ws_size,
                              hipStream_t stream) {
  const float* x     = (const float*)d_in[0];
  const float* Wq    = (const float*)d_in[1];
  const float* bq    = (const float*)d_in[2];
  const float* Wk    = (const float*)d_in[3];
  const float* bk    = (const float*)d_in[4];
  const float* Wv    = (const float*)d_in[5];
  const float* bv    = (const float*)d_in[6];
  const float* gamma = (const float*)d_in[7];
  float* out = (float*)d_out;

  char* wsp = (char*)d_ws;
  __hip_bfloat16* W16 = (__hip_bfloat16*)wsp;  wsp += (size_t)320 * NC * 2;
  __hip_bfloat16* q   = (__hip_bfloat16*)wsp;  wsp += (size_t)NB * NN * DQK * 2;
  __hip_bfloat16* kT  = (__hip_bfloat16*)wsp;  wsp += (size_t)NB * NN * DQK * 2;
  __hip_bfloat16* v   = (__hip_bfloat16*)wsp;  // + 8.4 MB => ~10.6 MB total

  wcvt_kernel<<<dim3(80), dim3(256), 0, stream>>>(Wq, Wk, Wv, W16);
  proj_kernel<<<dim3(NN / 32, NB), dim3(256), 0, stream>>>(x, W16, bq, bk, bv, q, kT, v);
  flash_kernel<<<dim3(NB * NN / MT), dim3(512), 0, stream>>>(q, kT, v, x, gamma, out);
}